// Round 1
// baseline (483.318 us; speedup 1.0000x reference)
//
#include <hip/hip_runtime.h>
#include <math.h>

// Problem constants
#define NROWS 19200   // N*L = 4*4800
#define SLEN  4800
#define CDIM  256
#define HEADS 8
#define HD    32
#define KV_CHUNKS 15
#define KV_SC     320  // 4800/15

enum { EPI_NONE = 0, EPI_ROT_ELU = 1, EPI_SCALE = 2, EPI_RELU = 3 };

// out[m,n] = sum_k A[m,k] * W[n,k]   (i.e. A @ W.T), A row-major [M,lda>=K],
// W row-major [Nn,K]. 64x64 tile, BK=32, 256 threads, 4x4 acc per thread.
template <int EPI, bool CONCAT>
__global__ __launch_bounds__(256) void gemm_bt(
    const float* __restrict__ A0, const float* __restrict__ A1,
    const float* __restrict__ W, float* __restrict__ out,
    int M, int Nn, int K, int lda,
    const float* __restrict__ pe, float scale) {
  __shared__ float As[32][68];
  __shared__ float Ws[32][68];
  const int bm = blockIdx.y * 64, bn = blockIdx.x * 64;
  const int tid = threadIdx.x;
  const int tx = tid & 15, ty = tid >> 4;
  float acc[4][4] = {};

  for (int k0 = 0; k0 < K; k0 += 32) {
    __syncthreads();
#pragma unroll
    for (int q = 0; q < 2; ++q) {
      int cidx = q * 256 + tid;   // 0..511 float4 chunks
      int row = cidx >> 3;        // 0..63
      int kc = (cidx & 7) << 2;   // 0,4,..,28
      int kg = k0 + kc;
      float4 av, wv;
      if (CONCAT) {
        const float* Ap = (kg < 256) ? A0 : A1;
        int k2 = (kg < 256) ? kg : (kg - 256);
        av = *(const float4*)&Ap[(size_t)(bm + row) * 256 + k2];
      } else {
        av = *(const float4*)&A0[(size_t)(bm + row) * lda + kg];
      }
      wv = *(const float4*)&W[(size_t)(bn + row) * K + kg];
      As[kc + 0][row] = av.x; As[kc + 1][row] = av.y;
      As[kc + 2][row] = av.z; As[kc + 3][row] = av.w;
      Ws[kc + 0][row] = wv.x; Ws[kc + 1][row] = wv.y;
      Ws[kc + 2][row] = wv.z; Ws[kc + 3][row] = wv.w;
    }
    __syncthreads();
#pragma unroll 8
    for (int kk = 0; kk < 32; ++kk) {
      float4 a4 = *(const float4*)&As[kk][ty * 4];
      float4 w4 = *(const float4*)&Ws[kk][tx * 4];
      float av_[4] = {a4.x, a4.y, a4.z, a4.w};
      float wv_[4] = {w4.x, w4.y, w4.z, w4.w};
#pragma unroll
      for (int i = 0; i < 4; ++i)
#pragma unroll
        for (int j = 0; j < 4; ++j) acc[i][j] += av_[i] * wv_[j];
    }
  }

  const int orow = bm + ty * 4, ocol = bn + tx * 4;
#pragma unroll
  for (int i = 0; i < 4; ++i) {
    float r0 = acc[i][0], r1 = acc[i][1], r2 = acc[i][2], r3 = acc[i][3];
    if (EPI == EPI_ROT_ELU) {
      // rotary: t2[2i]=-t[2i+1], t2[2i+1]=t[2i]; out = t*cos + t2*sin
      const float* pp = &pe[((size_t)(orow + i) * 256 + ocol) * 2];
      float4 p0 = *(const float4*)&pp[0];  // c0 s0 c1 s1
      float4 p1 = *(const float4*)&pp[4];  // c2 s2 c3 s3
      float u0 = r0 * p0.x - r1 * p0.y;
      float u1 = r1 * p0.z + r0 * p0.w;
      float u2 = r2 * p1.x - r3 * p1.y;
      float u3 = r3 * p1.z + r2 * p1.w;
      // phi(x) = elu(x)+1 = x+1 (x>0) else exp(x)
      r0 = u0 > 0.f ? u0 + 1.f : expf(u0);
      r1 = u1 > 0.f ? u1 + 1.f : expf(u1);
      r2 = u2 > 0.f ? u2 + 1.f : expf(u2);
      r3 = u3 > 0.f ? u3 + 1.f : expf(u3);
    } else if (EPI == EPI_SCALE) {
      r0 *= scale; r1 *= scale; r2 *= scale; r3 *= scale;
    } else if (EPI == EPI_RELU) {
      r0 = fmaxf(r0, 0.f); r1 = fmaxf(r1, 0.f);
      r2 = fmaxf(r2, 0.f); r3 = fmaxf(r3, 0.f);
    }
    *(float4*)&out[(size_t)(orow + i) * Nn + ocol] = make_float4(r0, r1, r2, r3);
  }
}

// Partial KV[d][v] = sum_s K[n,s,h,d]*V[n,s,h,v] and Ksum[d] over a chunk of s.
// grid: (N*H)*KV_CHUNKS blocks, 256 threads.
__global__ __launch_bounds__(256) void kv_partial(
    const float* __restrict__ Kb, const float* __restrict__ Vb,
    float* __restrict__ kvp, float* __restrict__ ksp) {
  __shared__ float bufK[8][32];
  __shared__ float bufV[8][32];
  const int b = blockIdx.x;
  const int ch = b % KV_CHUNKS;
  const int nh = b / KV_CHUNKS;      // n*8+h
  const int h = nh & 7, n = nh >> 3;
  const int tid = threadIdx.x;
  const int d = tid >> 3, vb = (tid & 7) * 4;
  const int ssl = tid >> 5, lane = tid & 31;
  float a0 = 0.f, a1 = 0.f, a2 = 0.f, a3 = 0.f, ks = 0.f;
  const size_t base = (size_t)n * SLEN * 256 + (size_t)h * 32;
  const int s0 = ch * KV_SC;
  for (int s = s0; s < s0 + KV_SC; s += 8) {
    __syncthreads();
    size_t idx = base + (size_t)(s + ssl) * 256 + lane;
    bufK[ssl][lane] = Kb[idx];
    bufV[ssl][lane] = Vb[idx];
    __syncthreads();
#pragma unroll
    for (int ss = 0; ss < 8; ++ss) {
      float kd = bufK[ss][d];
      float4 vv = *(const float4*)&bufV[ss][vb];
      a0 += kd * vv.x; a1 += kd * vv.y; a2 += kd * vv.z; a3 += kd * vv.w;
      ks += kd;
    }
  }
  float* kv = &kvp[(size_t)b * 1024 + d * 32 + vb];
  kv[0] = a0; kv[1] = a1; kv[2] = a2; kv[3] = a3;
  if ((tid & 7) == 0) ksp[(size_t)b * 32 + d] = ks;
}

// Reduce partials: grid 32 (=N*H), 256 threads.
__global__ __launch_bounds__(256) void kv_reduce(
    const float* __restrict__ kvp, const float* __restrict__ ksp,
    float* __restrict__ KV, float* __restrict__ Ksum) {
  const int nh = blockIdx.x;
  const int tid = threadIdx.x;
  for (int e = tid; e < 1024; e += 256) {
    float s = 0.f;
    for (int p = 0; p < KV_CHUNKS; ++p)
      s += kvp[(size_t)(nh * KV_CHUNKS + p) * 1024 + e];
    KV[(size_t)nh * 1024 + e] = s;
  }
  if (tid < 32) {
    float s = 0.f;
    for (int p = 0; p < KV_CHUNKS; ++p)
      s += ksp[(size_t)(nh * KV_CHUNKS + p) * 32 + tid];
    Ksum[nh * 32 + tid] = s;
  }
}

// msg[r, h*32+v] = (sum_d Q[r,h*32+d]*KV[nh,d,v]) * z * 4800,
// z = 1/(dot(Q_h, Ksum_h) + eps). grid 19200, 256 threads.
__global__ __launch_bounds__(256) void msg_kernel(
    const float* __restrict__ Qb, const float* __restrict__ KV,
    const float* __restrict__ Ksum, float* __restrict__ msg) {
  __shared__ float Qs[256];
  const int r = blockIdx.x;
  const int tid = threadIdx.x;
  const int n = r / SLEN;
  Qs[tid] = Qb[(size_t)r * 256 + tid];
  __syncthreads();
  const int h = tid >> 5, v = tid & 31;
  const float* kvh = &KV[(size_t)(n * 8 + h) * 1024];
  const float* ksh = &Ksum[(n * 8 + h) * 32];
  const float* qh = &Qs[h * 32];
  float z = 0.f, m = 0.f;
#pragma unroll 8
  for (int d = 0; d < 32; ++d) {
    float qd = qh[d];
    z += qd * ksh[d];
    m += qd * kvh[d * 32 + v];
  }
  z = 1.0f / (z + 1e-6f);
  msg[(size_t)r * 256 + tid] = m * z * 4800.0f;
}

// LayerNorm over 256 cols; one wave per row, 4 rows/block.
template <bool RESID>
__global__ __launch_bounds__(256) void ln_kernel(
    const float* __restrict__ in, const float* __restrict__ g,
    const float* __restrict__ bb, const float* __restrict__ resid,
    float* __restrict__ out) {
  const int lane = threadIdx.x & 63;
  const int r = blockIdx.x * 4 + (threadIdx.x >> 6);
  const float4 v = *(const float4*)&in[(size_t)r * 256 + lane * 4];
  float s = v.x + v.y + v.z + v.w;
#pragma unroll
  for (int o = 32; o; o >>= 1) s += __shfl_down(s, o);
  float mu = __shfl(s, 0) * (1.0f / 256.0f);
  float dx = v.x - mu, dy = v.y - mu, dz = v.z - mu, dw = v.w - mu;
  float sq = dx * dx + dy * dy + dz * dz + dw * dw;
#pragma unroll
  for (int o = 32; o; o >>= 1) sq += __shfl_down(sq, o);
  float var = __shfl(sq, 0) * (1.0f / 256.0f);
  float rs = rsqrtf(var + 1e-5f);
  float4 gg = *(const float4*)&g[lane * 4];
  float4 b4 = *(const float4*)&bb[lane * 4];
  float4 o4;
  o4.x = dx * rs * gg.x + b4.x;
  o4.y = dy * rs * gg.y + b4.y;
  o4.z = dz * rs * gg.z + b4.z;
  o4.w = dw * rs * gg.w + b4.w;
  if (RESID) {
    const float4 rr = *(const float4*)&resid[(size_t)r * 256 + lane * 4];
    o4.x += rr.x; o4.y += rr.y; o4.z += rr.z; o4.w += rr.w;
  }
  *(float4*)&out[(size_t)r * 256 + lane * 4] = o4;
}

extern "C" void kernel_launch(void* const* d_in, const int* in_sizes, int n_in,
                              void* d_out, int out_size, void* d_ws,
                              size_t ws_size, hipStream_t stream) {
  const float* x    = (const float*)d_in[0];
  const float* src  = (const float*)d_in[1];
  const float* x_pe = (const float*)d_in[2];
  const float* s_pe = (const float*)d_in[3];
  const float* Wq = (const float*)d_in[4];
  const float* Wk = (const float*)d_in[5];
  const float* Wv = (const float*)d_in[6];
  const float* Wm = (const float*)d_in[7];
  const float* W1 = (const float*)d_in[8];
  const float* W2 = (const float*)d_in[9];
  const float* g1 = (const float*)d_in[10];
  const float* b1 = (const float*)d_in[11];
  const float* g2 = (const float*)d_in[12];
  const float* b2 = (const float*)d_in[13];
  float* out = (float*)d_out;

  float* ws = (float*)d_ws;
  const size_t R = (size_t)NROWS * 256;  // 4,915,200
  float* Q     = ws;                 // R
  float* Kb    = ws + R;             // R
  float* Vb    = ws + 2 * R;         // R
  float* msg   = ws + 3 * R;         // R
  float* msgln = ws + 4 * R;         // R
  float* kvp   = ws + 5 * R;                    // 15*32*1024 = 491520
  float* ksp   = kvp + 491520;                  // 15360
  float* KV    = ksp + 15360;                   // 32768
  float* Ksum  = KV + 32768;                    // 1024
  float* mergeout = Q;   // Q dead after msg_kernel
  float* h1 = Kb;        // Kb+Vb dead after kv_partial (2R contiguous)
  float* h2 = msg;       // msg dead after merge gemm

  dim3 blk(256);
  // q = phi(rotary(x @ Wq.T))
  gemm_bt<EPI_ROT_ELU, false><<<dim3(4, 300), blk, 0, stream>>>(
      x, nullptr, Wq, Q, NROWS, 256, 256, 256, x_pe, 0.f);
  // k = phi(rotary(src @ Wk.T))
  gemm_bt<EPI_ROT_ELU, false><<<dim3(4, 300), blk, 0, stream>>>(
      src, nullptr, Wk, Kb, NROWS, 256, 256, 256, s_pe, 0.f);
  // vals = (src @ Wv.T) / 4800
  gemm_bt<EPI_SCALE, false><<<dim3(4, 300), blk, 0, stream>>>(
      src, nullptr, Wv, Vb, NROWS, 256, 256, 256, nullptr, 1.0f / 4800.0f);
  // KV + Ksum
  kv_partial<<<dim3(32 * KV_CHUNKS), blk, 0, stream>>>(Kb, Vb, kvp, ksp);
  kv_reduce<<<dim3(32), blk, 0, stream>>>(kvp, ksp, KV, Ksum);
  // msg
  msg_kernel<<<dim3(NROWS), blk, 0, stream>>>(Q, KV, Ksum, msg);
  // merge: msg @ Wm.T
  gemm_bt<EPI_NONE, false><<<dim3(4, 300), blk, 0, stream>>>(
      msg, nullptr, Wm, mergeout, NROWS, 256, 256, 256, nullptr, 0.f);
  // norm1
  ln_kernel<false><<<dim3(NROWS / 4), blk, 0, stream>>>(
      mergeout, g1, b1, nullptr, msgln);
  // MLP1: relu([x, msgln] @ W1.T)  -> h1 [NROWS,512]
  gemm_bt<EPI_RELU, true><<<dim3(8, 300), blk, 0, stream>>>(
      x, msgln, W1, h1, NROWS, 512, 512, 256, nullptr, 0.f);
  // MLP2: h1 @ W2.T -> h2 [NROWS,256]
  gemm_bt<EPI_NONE, false><<<dim3(4, 300), blk, 0, stream>>>(
      h1, nullptr, W2, h2, NROWS, 256, 512, 512, nullptr, 0.f);
  // out = x + LN(h2)
  ln_kernel<true><<<dim3(NROWS / 4), blk, 0, stream>>>(h2, g2, b2, x, out);
}

// Round 2
// 165.673 us; speedup vs baseline: 2.9173x; 2.9173x over previous
//
#include <hip/hip_runtime.h>
#include <hip/hip_bf16.h>
#include <math.h>

#define NROWS 19200   // N*L = 4*4800
#define SLEN  4800
#define KV_CHUNKS 15
#define KV_SC     320

typedef unsigned short ushort_t;
typedef __attribute__((ext_vector_type(8))) short bf16x8;
typedef __attribute__((ext_vector_type(4))) float f32x4;
typedef __attribute__((ext_vector_type(8))) unsigned short ushort8;

__device__ __forceinline__ float bf2f(ushort_t u) {
  union { unsigned int i; float f; } x; x.i = ((unsigned int)u) << 16; return x.f;
}
__device__ __forceinline__ ushort_t f2bf(float f) {
  __hip_bfloat16 h = __float2bfloat16(f);
  union { __hip_bfloat16 h; ushort_t u; } x; x.h = h; return x.u;
}

#define GLOAD16(g, l) __builtin_amdgcn_global_load_lds( \
    (const __attribute__((address_space(1))) unsigned int*)(g), \
    (__attribute__((address_space(3))) unsigned int*)(l), 16, 0, 0)

// ---------------- bf16 MFMA GEMM: out = A @ W.T (+epilogue) ----------------
// A row-major [M, lda] bf16, W row-major [Nn, K] bf16. BM=128, BK=64.
// EPI: 0 none, 1 rotary+elu+1 (pe), 3 relu.
template <int BN, int EPI, bool CONCAT, bool OUTBF>
__device__ __forceinline__ void gemm_body(
    const ushort_t* __restrict__ A0, const ushort_t* __restrict__ A1,
    const ushort_t* __restrict__ W, void* __restrict__ outp,
    const float* __restrict__ pe,
    int Nn, int K, int lda, int bm, int bn, char* smem) {
  constexpr int BM = 128, BK = 64;
  constexpr int NI = BN / 32;
  constexpr int CH_A = BM * BK * 2 / 1024;  // 16 chunks of 1KB
  constexpr int CH_B = BN * BK * 2 / 1024;  // 8 or 16
  const int tid = threadIdx.x;
  const int wave = tid >> 6, lane = tid & 63;
  const int wm = (wave >> 1) * 64, wn = (wave & 1) * (BN / 2);
  const int l15 = lane & 15, l4 = lane >> 4;

  f32x4 acc[4][NI];
#pragma unroll
  for (int i = 0; i < 4; ++i)
#pragma unroll
    for (int j = 0; j < NI; ++j) acc[i][j] = (f32x4){0.f, 0.f, 0.f, 0.f};

  for (int k0 = 0; k0 < K; k0 += BK) {
    const ushort_t* Asrc;
    int ka;
    if (CONCAT) { Asrc = (k0 < 256) ? A0 : A1; ka = k0 & 255; }
    else        { Asrc = A0; ka = k0; }
    // stage A tile [BM][BK], swizzled: granule g holds global granule g^(row&7)
#pragma unroll
    for (int c = 0; c < CH_A / 4; ++c) {
      int ch = c * 4 + wave;
      int o = ch * 1024 + lane * 16;
      int row = o >> 7, g = (o >> 4) & 7;
      const ushort_t* src =
          Asrc + (size_t)(bm + row) * lda + ka + ((g ^ (row & 7)) << 3);
      GLOAD16(src, smem + ch * 1024);
    }
    // stage B tile [BN][BK]
#pragma unroll
    for (int c = 0; c < CH_B / 4; ++c) {
      int ch = c * 4 + wave;
      int o = ch * 1024 + lane * 16;
      int row = o >> 7, g = (o >> 4) & 7;
      const ushort_t* src =
          W + (size_t)(bn + row) * K + k0 + ((g ^ (row & 7)) << 3);
      GLOAD16(src, smem + BM * BK * 2 + ch * 1024);
    }
    __syncthreads();
#pragma unroll
    for (int kc = 0; kc < 2; ++kc) {
      bf16x8 af[4], bfr[NI];
#pragma unroll
      for (int mi = 0; mi < 4; ++mi) {
        int r = wm + mi * 16 + l15;
        int G = kc * 4 + l4;
        af[mi] = *(const bf16x8*)(smem + r * 128 + ((G ^ (r & 7)) << 4));
      }
#pragma unroll
      for (int ni = 0; ni < NI; ++ni) {
        int r = wn + ni * 16 + l15;
        int G = kc * 4 + l4;
        bfr[ni] = *(const bf16x8*)(smem + BM * BK * 2 + r * 128 +
                                   ((G ^ (r & 7)) << 4));
      }
#pragma unroll
      for (int mi = 0; mi < 4; ++mi)
#pragma unroll
        for (int ni = 0; ni < NI; ++ni)
          acc[mi][ni] = __builtin_amdgcn_mfma_f32_16x16x32_bf16(
              af[mi], bfr[ni], acc[mi][ni], 0, 0, 0);
    }
    __syncthreads();
  }

  // epilogue + store. C/D layout: col = lane&15, row = (lane>>4)*4 + j.
#pragma unroll
  for (int mi = 0; mi < 4; ++mi) {
#pragma unroll
    for (int ni = 0; ni < NI; ++ni) {
#pragma unroll
      for (int j = 0; j < 4; ++j) {
        float v = acc[mi][ni][j];
        int gr = bm + wm + mi * 16 + l4 * 4 + j;
        int gc = bn + wn + ni * 16 + l15;
        if (EPI == 1) {
          float p = __shfl_xor(v, 1);  // partner col (2i <-> 2i+1)
          const float2 cs = *(const float2*)&pe[((size_t)gr * 256 + gc) * 2];
          float u = v * cs.x + ((gc & 1) ? p : -p) * cs.y;
          v = u > 0.f ? u + 1.f : __expf(u);
        } else if (EPI == 3) {
          v = fmaxf(v, 0.f);
        }
        if (OUTBF)
          ((ushort_t*)outp)[(size_t)gr * Nn + gc] = f2bf(v);
        else
          ((float*)outp)[(size_t)gr * Nn + gc] = v;
      }
    }
  }
}

template <int BN, int EPI, bool CONCAT, bool OUTBF>
__global__ __launch_bounds__(256) void gemm_kernel(
    const ushort_t* __restrict__ A0, const ushort_t* __restrict__ A1,
    const ushort_t* __restrict__ W, void* __restrict__ out,
    const float* __restrict__ pe, int Nn, int K, int lda) {
  extern __shared__ char smem[];
  const int nbn = Nn / BN;
  const int bm = (blockIdx.x / nbn) * 128, bn = (blockIdx.x % nbn) * BN;
  gemm_body<BN, EPI, CONCAT, OUTBF>(A0, A1, W, out, pe, Nn, K, lda, bm, bn, smem);
}

// q,k,v fused in one dispatch: blocks [0,300) q, [300,600) k, [600,900) v
__global__ __launch_bounds__(256) void qkv_kernel(
    const ushort_t* __restrict__ xb, const ushort_t* __restrict__ srcb,
    const ushort_t* __restrict__ Wqb, const ushort_t* __restrict__ Wkb,
    const ushort_t* __restrict__ Wvb,
    ushort_t* __restrict__ Q, ushort_t* __restrict__ Kb,
    ushort_t* __restrict__ Vb,
    const float* __restrict__ x_pe, const float* __restrict__ s_pe) {
  extern __shared__ char smem[];
  int b = blockIdx.x;
  if (b < 300) {
    int bm = (b >> 1) * 128, bn = (b & 1) * 128;
    gemm_body<128, 1, false, true>(xb, nullptr, Wqb, Q, x_pe, 256, 256, 256,
                                   bm, bn, smem);
  } else if (b < 600) {
    b -= 300;
    int bm = (b >> 1) * 128, bn = (b & 1) * 128;
    gemm_body<128, 1, false, true>(srcb, nullptr, Wkb, Kb, s_pe, 256, 256, 256,
                                   bm, bn, smem);
  } else {
    b -= 600;
    int bm = (b >> 1) * 128, bn = (b & 1) * 128;
    gemm_body<128, 0, false, true>(srcb, nullptr, Wvb, Vb, nullptr, 256, 256,
                                   256, bm, bn, smem);
  }
}

// ---------------- KV = sum_s K^T V (per n,h), Ksum = sum_s K ----------------
__global__ __launch_bounds__(256) void kv_partial(
    const ushort_t* __restrict__ Kb, const ushort_t* __restrict__ Vb,
    float* __restrict__ kvp, float* __restrict__ ksp) {
  __shared__ float bufK[8][32];
  __shared__ float bufV[8][32];
  const int b = blockIdx.x;
  const int ch = b % KV_CHUNKS;
  const int nh = b / KV_CHUNKS;
  const int h = nh & 7, n = nh >> 3;
  const int tid = threadIdx.x;
  const int d = tid >> 3, vb = (tid & 7) * 4;
  const int ssl = tid >> 5, lane = tid & 31;
  float a0 = 0.f, a1 = 0.f, a2 = 0.f, a3 = 0.f, ks = 0.f;
  const size_t base = (size_t)n * SLEN * 256 + (size_t)h * 32;
  const int s0 = ch * KV_SC;
  for (int s = s0; s < s0 + KV_SC; s += 8) {
    __syncthreads();
    size_t idx = base + (size_t)(s + ssl) * 256 + lane;
    bufK[ssl][lane] = bf2f(Kb[idx]);
    bufV[ssl][lane] = bf2f(Vb[idx]);
    __syncthreads();
#pragma unroll
    for (int ss = 0; ss < 8; ++ss) {
      float kd = bufK[ss][d];
      float4 vv = *(const float4*)&bufV[ss][vb];
      a0 += kd * vv.x; a1 += kd * vv.y; a2 += kd * vv.z; a3 += kd * vv.w;
      ks += kd;
    }
  }
  float* kv = &kvp[(size_t)b * 1024 + d * 32 + vb];
  kv[0] = a0; kv[1] = a1; kv[2] = a2; kv[3] = a3;
  if ((tid & 7) == 0) ksp[(size_t)b * 32 + d] = ks;
}

__global__ __launch_bounds__(256) void kv_reduce(
    const float* __restrict__ kvp, const float* __restrict__ ksp,
    float* __restrict__ KV, float* __restrict__ Ksum) {
  const int nh = blockIdx.x;
  const int tid = threadIdx.x;
  for (int e = tid; e < 1024; e += 256) {
    float s = 0.f;
    for (int p = 0; p < KV_CHUNKS; ++p)
      s += kvp[(size_t)(nh * KV_CHUNKS + p) * 1024 + e];
    KV[(size_t)nh * 1024 + e] = s;
  }
  if (tid < 32) {
    float s = 0.f;
    for (int p = 0; p < KV_CHUNKS; ++p)
      s += ksp[(size_t)(nh * KV_CHUNKS + p) * 32 + tid];
    Ksum[nh * 32 + tid] = s;
  }
}

// msg[r, h*32+v] = (Q_h . KVcol_v) / (Q_h . Ksum_h + eps); 8 rows per block
__global__ __launch_bounds__(256) void msg_kernel(
    const ushort_t* __restrict__ Qb, const float* __restrict__ KV,
    const float* __restrict__ Ksum, ushort_t* __restrict__ msg) {
  __shared__ float Qs[8][256];
  __shared__ float Ks[8][32];
  const int b = blockIdx.x;   // 2400 blocks
  const int r0 = b * 8;
  const int n = r0 / SLEN;
  const int tid = threadIdx.x;
  Ks[tid >> 5][tid & 31] = Ksum[(n * 8 + (tid >> 5)) * 32 + (tid & 31)];
  for (int i = tid; i < 512; i += 256) {
    int rr = i >> 6, cc = (i & 63) << 2;
    const ushort4 u = *(const ushort4*)&Qb[(size_t)(r0 + rr) * 256 + cc];
    Qs[rr][cc + 0] = bf2f(u.x); Qs[rr][cc + 1] = bf2f(u.y);
    Qs[rr][cc + 2] = bf2f(u.z); Qs[rr][cc + 3] = bf2f(u.w);
  }
  __syncthreads();
  const int h = tid >> 5, v = tid & 31;
  const float* kvh = &KV[(size_t)(n * 8 + h) * 1024 + v];
  float kvc[32];
#pragma unroll
  for (int d = 0; d < 32; ++d) kvc[d] = kvh[d * 32];
#pragma unroll
  for (int rr = 0; rr < 8; ++rr) {
    float z = 0.f, m = 0.f;
#pragma unroll
    for (int d = 0; d < 32; ++d) {
      float qd = Qs[rr][h * 32 + d];
      z += qd * Ks[h][d];
      m += qd * kvc[d];
    }
    z = 1.0f / (z + 1e-6f);
    msg[(size_t)(r0 + rr) * 256 + h * 32 + v] = f2bf(m * z);
  }
}

// ---------------- LayerNorm (256 cols), 1 wave/row, 4 rows/block ------------
template <bool RESID, bool OUTBF>
__global__ __launch_bounds__(256) void ln_kernel(
    const float* __restrict__ in, const float* __restrict__ g,
    const float* __restrict__ bb, const float* __restrict__ resid,
    void* __restrict__ outp) {
  const int lane = threadIdx.x & 63;
  const size_t r = (size_t)blockIdx.x * 4 + (threadIdx.x >> 6);
  const float4 v = *(const float4*)&in[r * 256 + lane * 4];
  float s = v.x + v.y + v.z + v.w;
#pragma unroll
  for (int o = 32; o; o >>= 1) s += __shfl_down(s, o);
  float mu = __shfl(s, 0) * (1.0f / 256.0f);
  float dx = v.x - mu, dy = v.y - mu, dz = v.z - mu, dw = v.w - mu;
  float sq = dx * dx + dy * dy + dz * dz + dw * dw;
#pragma unroll
  for (int o = 32; o; o >>= 1) sq += __shfl_down(sq, o);
  float var = __shfl(sq, 0) * (1.0f / 256.0f);
  float rs = rsqrtf(var + 1e-5f);
  float4 gg = *(const float4*)&g[lane * 4];
  float4 b4 = *(const float4*)&bb[lane * 4];
  float4 o4;
  o4.x = dx * rs * gg.x + b4.x;
  o4.y = dy * rs * gg.y + b4.y;
  o4.z = dz * rs * gg.z + b4.z;
  o4.w = dw * rs * gg.w + b4.w;
  if (RESID) {
    const float4 rr2 = *(const float4*)&resid[r * 256 + lane * 4];
    o4.x += rr2.x; o4.y += rr2.y; o4.z += rr2.z; o4.w += rr2.w;
  }
  if (OUTBF) {
    ushort4 u = make_ushort4(f2bf(o4.x), f2bf(o4.y), f2bf(o4.z), f2bf(o4.w));
    *(ushort4*)((ushort_t*)outp + r * 256 + lane * 4) = u;
  } else {
    *(float4*)((float*)outp + r * 256 + lane * 4) = o4;
  }
}

// ---------------- fp32 -> bf16 conversions ----------------
__global__ __launch_bounds__(256) void conv_pair(
    const float* __restrict__ a, const float* __restrict__ b,
    ushort_t* __restrict__ ao, ushort_t* __restrict__ bo) {
  int blk = blockIdx.x;
  const float* s; ushort_t* d;
  if (blk < 2400) { s = a; d = ao; } else { s = b; d = bo; blk -= 2400; }
  size_t o = ((size_t)blk * 256 + threadIdx.x) * 8;
  float4 v0 = *(const float4*)&s[o];
  float4 v1 = *(const float4*)&s[o + 4];
  ushort8 u = {f2bf(v0.x), f2bf(v0.y), f2bf(v0.z), f2bf(v0.w),
               f2bf(v1.x), f2bf(v1.y), f2bf(v1.z), f2bf(v1.w)};
  *(ushort8*)&d[o] = u;
}

__global__ __launch_bounds__(256) void conv_w(
    const float* w0, const float* w1, const float* w2, const float* w3,
    const float* w4, const float* w5,
    ushort_t* o0, ushort_t* o1, ushort_t* o2, ushort_t* o3, ushort_t* o4,
    ushort_t* o5) {
  int e = (blockIdx.x * 256 + threadIdx.x) * 4;
  const float* s; ushort_t* d; int off;
  if      (e < 65536)  { s = w0; d = o0; off = e; }
  else if (e < 131072) { s = w1; d = o1; off = e - 65536; }
  else if (e < 196608) { s = w2; d = o2; off = e - 131072; }
  else if (e < 262144) { s = w3; d = o3; off = e - 196608; }
  else if (e < 524288) { s = w4; d = o4; off = e - 262144; }
  else                 { s = w5; d = o5; off = e - 524288; }
  float4 v = *(const float4*)&s[off];
  ushort4 u = make_ushort4(f2bf(v.x), f2bf(v.y), f2bf(v.z), f2bf(v.w));
  *(ushort4*)&d[off] = u;
}

extern "C" void kernel_launch(void* const* d_in, const int* in_sizes, int n_in,
                              void* d_out, int out_size, void* d_ws,
                              size_t ws_size, hipStream_t stream) {
  const float* x    = (const float*)d_in[0];
  const float* src  = (const float*)d_in[1];
  const float* x_pe = (const float*)d_in[2];
  const float* s_pe = (const float*)d_in[3];
  const float* Wq = (const float*)d_in[4];
  const float* Wk = (const float*)d_in[5];
  const float* Wv = (const float*)d_in[6];
  const float* Wm = (const float*)d_in[7];
  const float* W1 = (const float*)d_in[8];
  const float* W2 = (const float*)d_in[9];
  const float* g1 = (const float*)d_in[10];
  const float* b1 = (const float*)d_in[11];
  const float* g2 = (const float*)d_in[12];
  const float* b2 = (const float*)d_in[13];
  float* out = (float*)d_out;

  const size_t R = (size_t)NROWS * 256;  // 4,915,200
  ushort_t* xb    = (ushort_t*)d_ws;
  ushort_t* srcb  = xb + R;
  ushort_t* Qb    = srcb + R;
  ushort_t* Kb    = Qb + R;
  ushort_t* Vb    = Kb + R;
  ushort_t* msgln = Vb + R;
  ushort_t* Wqb   = msgln + R;
  ushort_t* Wkb   = Wqb + 65536;
  ushort_t* Wvb   = Wkb + 65536;
  ushort_t* Wmb   = Wvb + 65536;
  ushort_t* W1b   = Wmb + 65536;
  ushort_t* W2b   = W1b + 262144;
  float* mergeout = (float*)(W2b + 131072);
  float* kvp      = mergeout + R;     // 491520
  float* ksp      = kvp + 491520;     // 15360
  float* KVb      = ksp + 15360;      // 32768
  float* Ksum     = KVb + 32768;      // 1024
  ushort_t* msgb = srcb;   // srcb dead after qkv
  ushort_t* h1   = Kb;     // Kb+Vb dead after kv_partial (2R contiguous)
  float*    h2   = mergeout;  // dead after ln1

  dim3 blk(256);
  conv_pair<<<4800, blk, 0, stream>>>(x, src, xb, srcb);
  conv_w<<<640, blk, 0, stream>>>(Wq, Wk, Wv, Wm, W1, W2,
                                  Wqb, Wkb, Wvb, Wmb, W1b, W2b);
  qkv_kernel<<<900, blk, 32768, stream>>>(xb, srcb, Wqb, Wkb, Wvb, Qb, Kb, Vb,
                                          x_pe, s_pe);
  kv_partial<<<480, blk, 0, stream>>>(Kb, Vb, kvp, ksp);
  kv_reduce<<<32, blk, 0, stream>>>(kvp, ksp, KVb, Ksum);
  msg_kernel<<<2400, blk, 0, stream>>>(Qb, KVb, Ksum, msgb);
  // merge: msg @ Wm.T -> fp32
  gemm_kernel<64, 0, false, false><<<600, blk, 24576, stream>>>(
      msgb, nullptr, Wmb, mergeout, nullptr, 256, 256, 256);
  ln_kernel<false, true><<<4800, blk, 0, stream>>>(mergeout, g1, b1, nullptr,
                                                   msgln);
  // MLP1: relu([xb, msgln] @ W1.T) -> bf16 h1 [19200,512]
  gemm_kernel<128, 3, true, true><<<600, blk, 32768, stream>>>(
      xb, msgln, W1b, h1, nullptr, 512, 512, 256);
  // MLP2: h1 @ W2.T -> fp32 h2
  gemm_kernel<64, 0, false, false><<<600, blk, 24576, stream>>>(
      h1, nullptr, W2b, h2, nullptr, 256, 512, 512);
  // out = x + LN(h2)
  ln_kernel<true, false><<<4800, blk, 0, stream>>>(h2, g2, b2, x, out);
}

// Round 3
// 156.776 us; speedup vs baseline: 3.0829x; 1.0567x over previous
//
#include <hip/hip_runtime.h>
#include <hip/hip_bf16.h>
#include <math.h>

#define NROWS 19200   // N*L = 4*4800
#define SLEN  4800
#define KV_CHUNKS 15
#define KV_SC     320

typedef unsigned short ushort_t;
typedef __attribute__((ext_vector_type(8))) short bf16x8;
typedef __attribute__((ext_vector_type(4))) float f32x4;
typedef __attribute__((ext_vector_type(8))) unsigned short ushort8;

__device__ __forceinline__ float bf2f(ushort_t u) {
  union { unsigned int i; float f; } x; x.i = ((unsigned int)u) << 16; return x.f;
}
__device__ __forceinline__ ushort_t f2bf(float f) {
  __hip_bfloat16 h = __float2bfloat16(f);
  union { __hip_bfloat16 h; ushort_t u; } x; x.h = h; return x.u;
}

#define GLOAD16(g, l) __builtin_amdgcn_global_load_lds( \
    (const __attribute__((address_space(1))) unsigned int*)(g), \
    (__attribute__((address_space(3))) unsigned int*)(l), 16, 0, 0)

// ---------------- bf16 MFMA GEMM: out = A @ W.T (+epilogue) ----------------
// A row-major [M, lda] bf16, W row-major [Nn, K] bf16. BM=128.
// EPI: 0 none, 1 rotary+elu+1 (pe), 3 relu.
template <int BN, int EPI, bool CONCAT, bool OUTBF>
__device__ __forceinline__ void gemm_body(
    const ushort_t* __restrict__ A0, const ushort_t* __restrict__ A1,
    const ushort_t* __restrict__ W, void* __restrict__ outp,
    const float* __restrict__ pe,
    int Nn, int K, int lda, int bm, int bn, char* smem) {
  constexpr int BM = 128, BK = 64;
  constexpr int NI = BN / 32;
  constexpr int CH_A = BM * BK * 2 / 1024;  // 16 chunks of 1KB
  constexpr int CH_B = BN * BK * 2 / 1024;  // 8 or 16
  const int tid = threadIdx.x;
  const int wave = tid >> 6, lane = tid & 63;
  const int wm = (wave >> 1) * 64, wn = (wave & 1) * (BN / 2);
  const int l15 = lane & 15, l4 = lane >> 4;

  f32x4 acc[4][NI];
#pragma unroll
  for (int i = 0; i < 4; ++i)
#pragma unroll
    for (int j = 0; j < NI; ++j) acc[i][j] = (f32x4){0.f, 0.f, 0.f, 0.f};

  for (int k0 = 0; k0 < K; k0 += BK) {
    const ushort_t* Asrc;
    int ka;
    if (CONCAT) { Asrc = (k0 < 256) ? A0 : A1; ka = k0 & 255; }
    else        { Asrc = A0; ka = k0; }
    // stage A tile [BM][BK], swizzled: LDS granule g holds global granule g^(row&7)
#pragma unroll
    for (int c = 0; c < CH_A / 4; ++c) {
      int ch = c * 4 + wave;
      int o = ch * 1024 + lane * 16;
      int row = o >> 7, g = (o >> 4) & 7;
      const ushort_t* src =
          Asrc + (size_t)(bm + row) * lda + ka + ((g ^ (row & 7)) << 3);
      GLOAD16(src, smem + ch * 1024);
    }
    // stage B tile [BN][BK]
#pragma unroll
    for (int c = 0; c < CH_B / 4; ++c) {
      int ch = c * 4 + wave;
      int o = ch * 1024 + lane * 16;
      int row = o >> 7, g = (o >> 4) & 7;
      const ushort_t* src =
          W + (size_t)(bn + row) * K + k0 + ((g ^ (row & 7)) << 3);
      GLOAD16(src, smem + BM * BK * 2 + ch * 1024);
    }
    __syncthreads();
#pragma unroll
    for (int kc = 0; kc < 2; ++kc) {
      bf16x8 af[4], bfr[NI];
#pragma unroll
      for (int mi = 0; mi < 4; ++mi) {
        int r = wm + mi * 16 + l15;
        int G = kc * 4 + l4;
        af[mi] = *(const bf16x8*)(smem + r * 128 + ((G ^ (r & 7)) << 4));
      }
#pragma unroll
      for (int ni = 0; ni < NI; ++ni) {
        int r = wn + ni * 16 + l15;
        int G = kc * 4 + l4;
        bfr[ni] = *(const bf16x8*)(smem + BM * BK * 2 + r * 128 +
                                   ((G ^ (r & 7)) << 4));
      }
#pragma unroll
      for (int mi = 0; mi < 4; ++mi)
#pragma unroll
        for (int ni = 0; ni < NI; ++ni)
          acc[mi][ni] = __builtin_amdgcn_mfma_f32_16x16x32_bf16(
              af[mi], bfr[ni], acc[mi][ni], 0, 0, 0);
    }
    __syncthreads();
  }

  // epilogue + store. C/D layout: col = lane&15, row = (lane>>4)*4 + j.
#pragma unroll
  for (int mi = 0; mi < 4; ++mi) {
#pragma unroll
    for (int ni = 0; ni < NI; ++ni) {
#pragma unroll
      for (int j = 0; j < 4; ++j) {
        float v = acc[mi][ni][j];
        int gr = bm + wm + mi * 16 + l4 * 4 + j;
        int gc = bn + wn + ni * 16 + l15;
        if (EPI == 1) {
          float p = __shfl_xor(v, 1);  // partner col (2i <-> 2i+1)
          const float2 cs = *(const float2*)&pe[((size_t)gr * 256 + gc) * 2];
          float u = v * cs.x + ((gc & 1) ? p : -p) * cs.y;
          v = u > 0.f ? u + 1.f : __expf(u);
        } else if (EPI == 3) {
          v = fmaxf(v, 0.f);
        }
        if (OUTBF)
          ((ushort_t*)outp)[(size_t)gr * Nn + gc] = f2bf(v);
        else
          ((float*)outp)[(size_t)gr * Nn + gc] = v;
      }
    }
  }
}

template <int BN, int EPI, bool CONCAT, bool OUTBF>
__global__ __launch_bounds__(256) void gemm_kernel(
    const ushort_t* __restrict__ A0, const ushort_t* __restrict__ A1,
    const ushort_t* __restrict__ W, void* __restrict__ out,
    const float* __restrict__ pe, int Nn, int K, int lda) {
  extern __shared__ char smem[];
  const int nbn = Nn / BN;
  const int bm = (blockIdx.x / nbn) * 128, bn = (blockIdx.x % nbn) * BN;
  gemm_body<BN, EPI, CONCAT, OUTBF>(A0, A1, W, out, pe, Nn, K, lda, bm, bn, smem);
}

// q,k,v fused: 1800 blocks of BM=128 x BN=64: [0,600) q, [600,1200) k, rest v
__global__ __launch_bounds__(256) void qkv_kernel(
    const ushort_t* __restrict__ xb, const ushort_t* __restrict__ srcb,
    const ushort_t* __restrict__ Wqb, const ushort_t* __restrict__ Wkb,
    const ushort_t* __restrict__ Wvb,
    ushort_t* __restrict__ Q, ushort_t* __restrict__ Kb,
    ushort_t* __restrict__ Vb,
    const float* __restrict__ x_pe, const float* __restrict__ s_pe) {
  extern __shared__ char smem[];
  int b = blockIdx.x;
  if (b < 600) {
    int bm = (b >> 2) * 128, bn = (b & 3) * 64;
    gemm_body<64, 1, false, true>(xb, nullptr, Wqb, Q, x_pe, 256, 256, 256,
                                  bm, bn, smem);
  } else if (b < 1200) {
    b -= 600;
    int bm = (b >> 2) * 128, bn = (b & 3) * 64;
    gemm_body<64, 1, false, true>(srcb, nullptr, Wkb, Kb, s_pe, 256, 256, 256,
                                  bm, bn, smem);
  } else {
    b -= 1200;
    int bm = (b >> 2) * 128, bn = (b & 3) * 64;
    gemm_body<64, 0, false, true>(srcb, nullptr, Wvb, Vb, nullptr, 256, 256,
                                  256, bm, bn, smem);
  }
}

// ------- Fused GEMM (out = A @ W.T) + row LayerNorm (+residual) -------------
// BM=32, BN=256 (full row), BK=64, 4 waves; wave w owns cols [w*64, w*64+64).
template <int KDIM, bool RESID, bool OUTBF>
__global__ __launch_bounds__(256) void gemm_ln_kernel(
    const ushort_t* __restrict__ A, const ushort_t* __restrict__ W,
    const float* __restrict__ g, const float* __restrict__ bb,
    const float* __restrict__ resid, void* __restrict__ outp) {
  __shared__ char As[32 * 128];    // 4 KB
  __shared__ char Bs[256 * 128];   // 32 KB
  __shared__ float partS[4][32];
  __shared__ float partQ[4][32];
  __shared__ float gS[256], bS[256];

  const int tid = threadIdx.x;
  const int wave = tid >> 6, lane = tid & 63;
  const int l15 = lane & 15, l4 = lane >> 4;
  const int bm = blockIdx.x * 32;

  gS[tid] = g[tid];
  bS[tid] = bb[tid];

  f32x4 acc[2][4];
#pragma unroll
  for (int i = 0; i < 2; ++i)
#pragma unroll
    for (int j = 0; j < 4; ++j) acc[i][j] = (f32x4){0.f, 0.f, 0.f, 0.f};

  for (int k0 = 0; k0 < KDIM; k0 += 64) {
    {  // A tile: 32x64 = 4KB, 1 chunk/thread
      int row = tid >> 3, gch = tid & 7;
      const ushort_t* src =
          A + (size_t)(bm + row) * KDIM + k0 + ((gch ^ (row & 7)) << 3);
      GLOAD16(src, As + tid * 16);
    }
#pragma unroll
    for (int c = 0; c < 8; ++c) {  // B tile: 256x64 = 32KB, 8 chunks/thread
      int ch = c * 256 + tid;
      int row = ch >> 3, gch = ch & 7;
      const ushort_t* src =
          W + (size_t)row * KDIM + k0 + ((gch ^ (row & 7)) << 3);
      GLOAD16(src, Bs + ch * 16);
    }
    __syncthreads();
#pragma unroll
    for (int kc = 0; kc < 2; ++kc) {
      bf16x8 af[2], bfr[4];
#pragma unroll
      for (int mi = 0; mi < 2; ++mi) {
        int r = mi * 16 + l15;
        int G = kc * 4 + l4;
        af[mi] = *(const bf16x8*)(As + r * 128 + ((G ^ (r & 7)) << 4));
      }
#pragma unroll
      for (int ni = 0; ni < 4; ++ni) {
        int r = wave * 64 + ni * 16 + l15;
        int G = kc * 4 + l4;
        bfr[ni] = *(const bf16x8*)(Bs + r * 128 + ((G ^ (r & 7)) << 4));
      }
#pragma unroll
      for (int mi = 0; mi < 2; ++mi)
#pragma unroll
        for (int ni = 0; ni < 4; ++ni)
          acc[mi][ni] = __builtin_amdgcn_mfma_f32_16x16x32_bf16(
              af[mi], bfr[ni], acc[mi][ni], 0, 0, 0);
    }
    __syncthreads();
  }

  // ---- row LayerNorm across the 4 waves ----
#pragma unroll
  for (int mi = 0; mi < 2; ++mi)
#pragma unroll
    for (int j = 0; j < 4; ++j) {
      float s = acc[mi][0][j] + acc[mi][1][j] + acc[mi][2][j] + acc[mi][3][j];
      float q = acc[mi][0][j] * acc[mi][0][j] + acc[mi][1][j] * acc[mi][1][j] +
                acc[mi][2][j] * acc[mi][2][j] + acc[mi][3][j] * acc[mi][3][j];
#pragma unroll
      for (int m = 1; m < 16; m <<= 1) {
        s += __shfl_xor(s, m);
        q += __shfl_xor(q, m);
      }
      if (l15 == 0) {
        int row = mi * 16 + l4 * 4 + j;
        partS[wave][row] = s;
        partQ[wave][row] = q;
      }
    }
  __syncthreads();

  float mu[2][4], rsv[2][4];
#pragma unroll
  for (int mi = 0; mi < 2; ++mi)
#pragma unroll
    for (int j = 0; j < 4; ++j) {
      int row = mi * 16 + l4 * 4 + j;
      float s = partS[0][row] + partS[1][row] + partS[2][row] + partS[3][row];
      float q2 = partQ[0][row] + partQ[1][row] + partQ[2][row] + partQ[3][row];
      float m_ = s * (1.f / 256.f);
      float var = q2 * (1.f / 256.f) - m_ * m_;
      mu[mi][j] = m_;
      rsv[mi][j] = rsqrtf(var + 1e-5f);
    }

#pragma unroll
  for (int mi = 0; mi < 2; ++mi)
#pragma unroll
    for (int ni = 0; ni < 4; ++ni)
#pragma unroll
      for (int j = 0; j < 4; ++j) {
        int row = mi * 16 + l4 * 4 + j;
        int col = wave * 64 + ni * 16 + l15;
        float v = (acc[mi][ni][j] - mu[mi][j]) * rsv[mi][j] * gS[col] + bS[col];
        size_t gr = (size_t)(bm + row);
        if (RESID) v += resid[gr * 256 + col];
        if (OUTBF)
          ((ushort_t*)outp)[gr * 256 + col] = f2bf(v);
        else
          ((float*)outp)[gr * 256 + col] = v;
      }
}

// ---------------- KV = sum_s K^T V (per n,h), Ksum = sum_s K ----------------
__global__ __launch_bounds__(256) void kv_partial(
    const ushort_t* __restrict__ Kb, const ushort_t* __restrict__ Vb,
    float* __restrict__ kvp, float* __restrict__ ksp) {
  __shared__ float bufK[8][32];
  __shared__ float bufV[8][32];
  const int b = blockIdx.x;
  const int ch = b % KV_CHUNKS;
  const int nh = b / KV_CHUNKS;
  const int h = nh & 7, n = nh >> 3;
  const int tid = threadIdx.x;
  const int d = tid >> 3, vb = (tid & 7) * 4;
  const int ssl = tid >> 5, lane = tid & 31;
  float a0 = 0.f, a1 = 0.f, a2 = 0.f, a3 = 0.f, ks = 0.f;
  const size_t base = (size_t)n * SLEN * 256 + (size_t)h * 32;
  const int s0 = ch * KV_SC;
  for (int s = s0; s < s0 + KV_SC; s += 8) {
    __syncthreads();
    size_t idx = base + (size_t)(s + ssl) * 256 + lane;
    bufK[ssl][lane] = bf2f(Kb[idx]);
    bufV[ssl][lane] = bf2f(Vb[idx]);
    __syncthreads();
#pragma unroll
    for (int ss = 0; ss < 8; ++ss) {
      float kd = bufK[ss][d];
      float4 vv = *(const float4*)&bufV[ss][vb];
      a0 += kd * vv.x; a1 += kd * vv.y; a2 += kd * vv.z; a3 += kd * vv.w;
      ks += kd;
    }
  }
  float* kv = &kvp[(size_t)b * 1024 + d * 32 + vb];
  kv[0] = a0; kv[1] = a1; kv[2] = a2; kv[3] = a3;
  if ((tid & 7) == 0) ksp[(size_t)b * 32 + d] = ks;
}

__global__ __launch_bounds__(256) void kv_reduce(
    const float* __restrict__ kvp, const float* __restrict__ ksp,
    float* __restrict__ KV, float* __restrict__ Ksum) {
  const int nh = blockIdx.x;
  const int tid = threadIdx.x;
  for (int e = tid; e < 1024; e += 256) {
    float s = 0.f;
    for (int p = 0; p < KV_CHUNKS; ++p)
      s += kvp[(size_t)(nh * KV_CHUNKS + p) * 1024 + e];
    KV[(size_t)nh * 1024 + e] = s;
  }
  if (tid < 32) {
    float s = 0.f;
    for (int p = 0; p < KV_CHUNKS; ++p)
      s += ksp[(size_t)(nh * KV_CHUNKS + p) * 32 + tid];
    Ksum[nh * 32 + tid] = s;
  }
}

// msg[r, h*32+v] = (Q_h . KVcol_v) / (Q_h . Ksum_h + eps); 8 rows per block
__global__ __launch_bounds__(256) void msg_kernel(
    const ushort_t* __restrict__ Qb, const float* __restrict__ KV,
    const float* __restrict__ Ksum, ushort_t* __restrict__ msg) {
  __shared__ float Qs[8][256];
  __shared__ float Ks[8][32];
  const int b = blockIdx.x;   // 2400 blocks
  const int r0 = b * 8;
  const int n = r0 / SLEN;
  const int tid = threadIdx.x;
  Ks[tid >> 5][tid & 31] = Ksum[(n * 8 + (tid >> 5)) * 32 + (tid & 31)];
  for (int i = tid; i < 512; i += 256) {
    int rr = i >> 6, cc = (i & 63) << 2;
    const ushort4 u = *(const ushort4*)&Qb[(size_t)(r0 + rr) * 256 + cc];
    Qs[rr][cc + 0] = bf2f(u.x); Qs[rr][cc + 1] = bf2f(u.y);
    Qs[rr][cc + 2] = bf2f(u.z); Qs[rr][cc + 3] = bf2f(u.w);
  }
  __syncthreads();
  const int h = tid >> 5, v = tid & 31;
  const float* kvh = &KV[(size_t)(n * 8 + h) * 1024 + v];
  float kvc[32];
#pragma unroll
  for (int d = 0; d < 32; ++d) kvc[d] = kvh[d * 32];
#pragma unroll
  for (int rr = 0; rr < 8; ++rr) {
    float z = 0.f, m = 0.f;
#pragma unroll
    for (int d = 0; d < 32; ++d) {
      float qd = Qs[rr][h * 32 + d];
      z += qd * Ks[h][d];
      m += qd * kvc[d];
    }
    z = 1.0f / (z + 1e-6f);
    msg[(size_t)(r0 + rr) * 256 + h * 32 + v] = f2bf(m * z);
  }
}

// ------- fp32 -> bf16 conversions, one dispatch: [0,4800) x/src, rest W -----
__global__ __launch_bounds__(256) void conv_all(
    const float* __restrict__ x, const float* __restrict__ src,
    const float* w0, const float* w1, const float* w2, const float* w3,
    const float* w4, const float* w5,
    ushort_t* __restrict__ xo, ushort_t* __restrict__ so,
    ushort_t* o0, ushort_t* o1, ushort_t* o2, ushort_t* o3, ushort_t* o4,
    ushort_t* o5) {
  int blk = blockIdx.x;
  if (blk < 4800) {
    const float* s; ushort_t* d;
    if (blk < 2400) { s = x; d = xo; } else { s = src; d = so; blk -= 2400; }
    size_t o = ((size_t)blk * 256 + threadIdx.x) * 8;
    float4 v0 = *(const float4*)&s[o];
    float4 v1 = *(const float4*)&s[o + 4];
    ushort8 u = {f2bf(v0.x), f2bf(v0.y), f2bf(v0.z), f2bf(v0.w),
                 f2bf(v1.x), f2bf(v1.y), f2bf(v1.z), f2bf(v1.w)};
    *(ushort8*)&d[o] = u;
  } else {
    int e = ((blk - 4800) * 256 + threadIdx.x) * 4;
    const float* s; ushort_t* d; int off;
    if      (e < 65536)  { s = w0; d = o0; off = e; }
    else if (e < 131072) { s = w1; d = o1; off = e - 65536; }
    else if (e < 196608) { s = w2; d = o2; off = e - 131072; }
    else if (e < 262144) { s = w3; d = o3; off = e - 196608; }
    else if (e < 524288) { s = w4; d = o4; off = e - 262144; }
    else                 { s = w5; d = o5; off = e - 524288; }
    float4 v = *(const float4*)&s[off];
    ushort4 u = make_ushort4(f2bf(v.x), f2bf(v.y), f2bf(v.z), f2bf(v.w));
    *(ushort4*)&d[off] = u;
  }
}

extern "C" void kernel_launch(void* const* d_in, const int* in_sizes, int n_in,
                              void* d_out, int out_size, void* d_ws,
                              size_t ws_size, hipStream_t stream) {
  const float* x    = (const float*)d_in[0];
  const float* src  = (const float*)d_in[1];
  const float* x_pe = (const float*)d_in[2];
  const float* s_pe = (const float*)d_in[3];
  const float* Wq = (const float*)d_in[4];
  const float* Wk = (const float*)d_in[5];
  const float* Wv = (const float*)d_in[6];
  const float* Wm = (const float*)d_in[7];
  const float* W1 = (const float*)d_in[8];
  const float* W2 = (const float*)d_in[9];
  const float* g1 = (const float*)d_in[10];
  const float* b1 = (const float*)d_in[11];
  const float* g2 = (const float*)d_in[12];
  const float* b2 = (const float*)d_in[13];
  float* out = (float*)d_out;

  const size_t R = (size_t)NROWS * 256;  // 4,915,200
  ushort_t* xb    = (ushort_t*)d_ws;
  ushort_t* srcb  = xb + R;
  ushort_t* Qb    = srcb + R;
  ushort_t* Kb    = Qb + R;
  ushort_t* Vb    = Kb + R;
  ushort_t* msgln = Vb + R;
  ushort_t* Wqb   = msgln + R;
  ushort_t* Wkb   = Wqb + 65536;
  ushort_t* Wvb   = Wkb + 65536;
  ushort_t* Wmb   = Wvb + 65536;
  ushort_t* W1b   = Wmb + 65536;
  ushort_t* W2b   = W1b + 262144;
  float* kvp      = (float*)(W2b + 131072);   // 491520 f32
  float* ksp      = kvp + 491520;             // 15360
  float* KVb      = ksp + 15360;              // 32768
  float* Ksum     = KVb + 32768;              // 1024
  ushort_t* msgb = srcb;   // srcb dead after qkv
  ushort_t* h1   = Kb;     // Kb+Vb dead after kv_partial (2R contiguous)

  dim3 blk(256);
  conv_all<<<5440, blk, 0, stream>>>(x, src, Wq, Wk, Wv, Wm, W1, W2,
                                     xb, srcb, Wqb, Wkb, Wvb, Wmb, W1b, W2b);
  qkv_kernel<<<1800, blk, 24576, stream>>>(xb, srcb, Wqb, Wkb, Wvb, Qb, Kb, Vb,
                                           x_pe, s_pe);
  kv_partial<<<480, blk, 0, stream>>>(Kb, Vb, kvp, ksp);
  kv_reduce<<<32, blk, 0, stream>>>(kvp, ksp, KVb, Ksum);
  msg_kernel<<<2400, blk, 0, stream>>>(Qb, KVb, Ksum, msgb);
  // merge + LN1: msgln = LN(msg @ Wm.T) (bf16)
  gemm_ln_kernel<256, false, true><<<600, blk, 0, stream>>>(
      msgb, Wmb, g1, b1, nullptr, msgln);
  // MLP1: h1 = relu([xb, msgln] @ W1.T) (bf16, [19200,512])
  gemm_kernel<64, 3, true, true><<<1200, blk, 24576, stream>>>(
      xb, msgln, W1b, h1, nullptr, 512, 512, 256);
  // MLP2 + LN2 + residual: out = x + LN(h1 @ W2.T) (fp32)
  gemm_ln_kernel<512, true, false><<<600, blk, 0, stream>>>(
      h1, W2b, g2, b2, x, out);
}

// Round 4
// 156.632 us; speedup vs baseline: 3.0857x; 1.0009x over previous
//
#include <hip/hip_runtime.h>
#include <hip/hip_bf16.h>
#include <math.h>

#define NROWS 19200   // N*L = 4*4800
#define SLEN  4800
#define KV_CHUNKS 15
#define KV_SC     320

typedef unsigned short ushort_t;
typedef __attribute__((ext_vector_type(8))) short bf16x8;
typedef __attribute__((ext_vector_type(4))) float f32x4;
typedef __attribute__((ext_vector_type(8))) unsigned short ushort8;

__device__ __forceinline__ float bf2f(ushort_t u) {
  union { unsigned int i; float f; } x; x.i = ((unsigned int)u) << 16; return x.f;
}
__device__ __forceinline__ ushort_t f2bf(float f) {
  __hip_bfloat16 h = __float2bfloat16(f);
  union { __hip_bfloat16 h; ushort_t u; } x; x.h = h; return x.u;
}

#define GLOAD16(g, l) __builtin_amdgcn_global_load_lds( \
    (const __attribute__((address_space(1))) unsigned int*)(g), \
    (__attribute__((address_space(3))) unsigned int*)(l), 16, 0, 0)

// ---------------- bf16 MFMA GEMM: out = A @ W.T (+epilogue) ----------------
// A row-major [M, lda] bf16, W row-major [Nn, K] bf16. BM=128.
// EPI: 0 none, 1 rotary+elu+1 (pe), 3 relu.
template <int BN, int EPI, bool CONCAT, bool OUTBF>
__device__ __forceinline__ void gemm_body(
    const ushort_t* __restrict__ A0, const ushort_t* __restrict__ A1,
    const ushort_t* __restrict__ W, void* __restrict__ outp,
    const float* __restrict__ pe,
    int Nn, int K, int lda, int bm, int bn, char* smem) {
  constexpr int BM = 128, BK = 64;
  constexpr int NI = BN / 32;
  constexpr int CH_A = BM * BK * 2 / 1024;  // 16 chunks of 1KB
  constexpr int CH_B = BN * BK * 2 / 1024;  // 8 or 16
  const int tid = threadIdx.x;
  const int wave = tid >> 6, lane = tid & 63;
  const int wm = (wave >> 1) * 64, wn = (wave & 1) * (BN / 2);
  const int l15 = lane & 15, l4 = lane >> 4;

  f32x4 acc[4][NI];
#pragma unroll
  for (int i = 0; i < 4; ++i)
#pragma unroll
    for (int j = 0; j < NI; ++j) acc[i][j] = (f32x4){0.f, 0.f, 0.f, 0.f};

  for (int k0 = 0; k0 < K; k0 += BK) {
    const ushort_t* Asrc;
    int ka;
    if (CONCAT) { Asrc = (k0 < 256) ? A0 : A1; ka = k0 & 255; }
    else        { Asrc = A0; ka = k0; }
    // stage A tile [BM][BK], swizzled: LDS granule g holds global granule g^(row&7)
#pragma unroll
    for (int c = 0; c < CH_A / 4; ++c) {
      int ch = c * 4 + wave;
      int o = ch * 1024 + lane * 16;
      int row = o >> 7, g = (o >> 4) & 7;
      const ushort_t* src =
          Asrc + (size_t)(bm + row) * lda + ka + ((g ^ (row & 7)) << 3);
      GLOAD16(src, smem + ch * 1024);
    }
    // stage B tile [BN][BK]
#pragma unroll
    for (int c = 0; c < CH_B / 4; ++c) {
      int ch = c * 4 + wave;
      int o = ch * 1024 + lane * 16;
      int row = o >> 7, g = (o >> 4) & 7;
      const ushort_t* src =
          W + (size_t)(bn + row) * K + k0 + ((g ^ (row & 7)) << 3);
      GLOAD16(src, smem + BM * BK * 2 + ch * 1024);
    }
    __syncthreads();
#pragma unroll
    for (int kc = 0; kc < 2; ++kc) {
      bf16x8 af[4], bfr[NI];
#pragma unroll
      for (int mi = 0; mi < 4; ++mi) {
        int r = wm + mi * 16 + l15;
        int G = kc * 4 + l4;
        af[mi] = *(const bf16x8*)(smem + r * 128 + ((G ^ (r & 7)) << 4));
      }
#pragma unroll
      for (int ni = 0; ni < NI; ++ni) {
        int r = wn + ni * 16 + l15;
        int G = kc * 4 + l4;
        bfr[ni] = *(const bf16x8*)(smem + BM * BK * 2 + r * 128 +
                                   ((G ^ (r & 7)) << 4));
      }
#pragma unroll
      for (int mi = 0; mi < 4; ++mi)
#pragma unroll
        for (int ni = 0; ni < NI; ++ni)
          acc[mi][ni] = __builtin_amdgcn_mfma_f32_16x16x32_bf16(
              af[mi], bfr[ni], acc[mi][ni], 0, 0, 0);
    }
    __syncthreads();
  }

  // epilogue + store. C/D layout: col = lane&15, row = (lane>>4)*4 + j.
#pragma unroll
  for (int mi = 0; mi < 4; ++mi) {
#pragma unroll
    for (int ni = 0; ni < NI; ++ni) {
#pragma unroll
      for (int j = 0; j < 4; ++j) {
        float v = acc[mi][ni][j];
        int gr = bm + wm + mi * 16 + l4 * 4 + j;
        int gc = bn + wn + ni * 16 + l15;
        if (EPI == 1) {
          float p = __shfl_xor(v, 1);  // partner col (2i <-> 2i+1)
          const float2 cs = *(const float2*)&pe[((size_t)gr * 256 + gc) * 2];
          float u = v * cs.x + ((gc & 1) ? p : -p) * cs.y;
          v = u > 0.f ? u + 1.f : __expf(u);
        } else if (EPI == 3) {
          v = fmaxf(v, 0.f);
        }
        if (OUTBF)
          ((ushort_t*)outp)[(size_t)gr * Nn + gc] = f2bf(v);
        else
          ((float*)outp)[(size_t)gr * Nn + gc] = v;
      }
    }
  }
}

template <int BN, int EPI, bool CONCAT, bool OUTBF>
__global__ __launch_bounds__(256) void gemm_kernel(
    const ushort_t* __restrict__ A0, const ushort_t* __restrict__ A1,
    const ushort_t* __restrict__ W, void* __restrict__ out,
    const float* __restrict__ pe, int Nn, int K, int lda) {
  extern __shared__ char smem[];
  const int nbn = Nn / BN;
  const int bm = (blockIdx.x / nbn) * 128, bn = (blockIdx.x % nbn) * BN;
  gemm_body<BN, EPI, CONCAT, OUTBF>(A0, A1, W, out, pe, Nn, K, lda, bm, bn, smem);
}

// q,k,v fused: 1800 blocks of BM=128 x BN=64: [0,600) q, [600,1200) k, rest v
__global__ __launch_bounds__(256) void qkv_kernel(
    const ushort_t* __restrict__ xb, const ushort_t* __restrict__ srcb,
    const ushort_t* __restrict__ Wqb, const ushort_t* __restrict__ Wkb,
    const ushort_t* __restrict__ Wvb,
    ushort_t* __restrict__ Q, ushort_t* __restrict__ Kb,
    ushort_t* __restrict__ Vb,
    const float* __restrict__ x_pe, const float* __restrict__ s_pe) {
  extern __shared__ char smem[];
  int b = blockIdx.x;
  if (b < 600) {
    int bm = (b >> 2) * 128, bn = (b & 3) * 64;
    gemm_body<64, 1, false, true>(xb, nullptr, Wqb, Q, x_pe, 256, 256, 256,
                                  bm, bn, smem);
  } else if (b < 1200) {
    b -= 600;
    int bm = (b >> 2) * 128, bn = (b & 3) * 64;
    gemm_body<64, 1, false, true>(srcb, nullptr, Wkb, Kb, s_pe, 256, 256, 256,
                                  bm, bn, smem);
  } else {
    b -= 1200;
    int bm = (b >> 2) * 128, bn = (b & 3) * 64;
    gemm_body<64, 0, false, true>(srcb, nullptr, Wvb, Vb, nullptr, 256, 256,
                                  256, bm, bn, smem);
  }
}

// ------- Fused GEMM (out = A @ W.T) + row LayerNorm (+residual) -------------
// BM=32, BN=256 (full row), BK=64, 4 waves; wave w owns cols [w*64, w*64+64).
template <int KDIM, bool RESID, bool OUTBF>
__global__ __launch_bounds__(256) void gemm_ln_kernel(
    const ushort_t* __restrict__ A, const ushort_t* __restrict__ W,
    const float* __restrict__ g, const float* __restrict__ bb,
    const float* __restrict__ resid, void* __restrict__ outp) {
  __shared__ char As[32 * 128];    // 4 KB
  __shared__ char Bs[256 * 128];   // 32 KB
  __shared__ float partS[4][32];
  __shared__ float partQ[4][32];
  __shared__ float gS[256], bS[256];

  const int tid = threadIdx.x;
  const int wave = tid >> 6, lane = tid & 63;
  const int l15 = lane & 15, l4 = lane >> 4;
  const int bm = blockIdx.x * 32;

  gS[tid] = g[tid];
  bS[tid] = bb[tid];

  f32x4 acc[2][4];
#pragma unroll
  for (int i = 0; i < 2; ++i)
#pragma unroll
    for (int j = 0; j < 4; ++j) acc[i][j] = (f32x4){0.f, 0.f, 0.f, 0.f};

  for (int k0 = 0; k0 < KDIM; k0 += 64) {
    {  // A tile: 32x64 = 4KB, 1 chunk/thread
      int row = tid >> 3, gch = tid & 7;
      const ushort_t* src =
          A + (size_t)(bm + row) * KDIM + k0 + ((gch ^ (row & 7)) << 3);
      GLOAD16(src, As + tid * 16);
    }
#pragma unroll
    for (int c = 0; c < 8; ++c) {  // B tile: 256x64 = 32KB, 8 chunks/thread
      int ch = c * 256 + tid;
      int row = ch >> 3, gch = ch & 7;
      const ushort_t* src =
          W + (size_t)row * KDIM + k0 + ((gch ^ (row & 7)) << 3);
      GLOAD16(src, Bs + ch * 16);
    }
    __syncthreads();
#pragma unroll
    for (int kc = 0; kc < 2; ++kc) {
      bf16x8 af[2], bfr[4];
#pragma unroll
      for (int mi = 0; mi < 2; ++mi) {
        int r = mi * 16 + l15;
        int G = kc * 4 + l4;
        af[mi] = *(const bf16x8*)(As + r * 128 + ((G ^ (r & 7)) << 4));
      }
#pragma unroll
      for (int ni = 0; ni < 4; ++ni) {
        int r = wave * 64 + ni * 16 + l15;
        int G = kc * 4 + l4;
        bfr[ni] = *(const bf16x8*)(Bs + r * 128 + ((G ^ (r & 7)) << 4));
      }
#pragma unroll
      for (int mi = 0; mi < 2; ++mi)
#pragma unroll
        for (int ni = 0; ni < 4; ++ni)
          acc[mi][ni] = __builtin_amdgcn_mfma_f32_16x16x32_bf16(
              af[mi], bfr[ni], acc[mi][ni], 0, 0, 0);
    }
    __syncthreads();
  }

  // ---- row LayerNorm across the 4 waves ----
#pragma unroll
  for (int mi = 0; mi < 2; ++mi)
#pragma unroll
    for (int j = 0; j < 4; ++j) {
      float s = acc[mi][0][j] + acc[mi][1][j] + acc[mi][2][j] + acc[mi][3][j];
      float q = acc[mi][0][j] * acc[mi][0][j] + acc[mi][1][j] * acc[mi][1][j] +
                acc[mi][2][j] * acc[mi][2][j] + acc[mi][3][j] * acc[mi][3][j];
#pragma unroll
      for (int m = 1; m < 16; m <<= 1) {
        s += __shfl_xor(s, m);
        q += __shfl_xor(q, m);
      }
      if (l15 == 0) {
        int row = mi * 16 + l4 * 4 + j;
        partS[wave][row] = s;
        partQ[wave][row] = q;
      }
    }
  __syncthreads();

  float mu[2][4], rsv[2][4];
#pragma unroll
  for (int mi = 0; mi < 2; ++mi)
#pragma unroll
    for (int j = 0; j < 4; ++j) {
      int row = mi * 16 + l4 * 4 + j;
      float s = partS[0][row] + partS[1][row] + partS[2][row] + partS[3][row];
      float q2 = partQ[0][row] + partQ[1][row] + partQ[2][row] + partQ[3][row];
      float m_ = s * (1.f / 256.f);
      float var = q2 * (1.f / 256.f) - m_ * m_;
      mu[mi][j] = m_;
      rsv[mi][j] = rsqrtf(var + 1e-5f);
    }

#pragma unroll
  for (int mi = 0; mi < 2; ++mi)
#pragma unroll
    for (int ni = 0; ni < 4; ++ni)
#pragma unroll
      for (int j = 0; j < 4; ++j) {
        int row = mi * 16 + l4 * 4 + j;
        int col = wave * 64 + ni * 16 + l15;
        float v = (acc[mi][ni][j] - mu[mi][j]) * rsv[mi][j] * gS[col] + bS[col];
        size_t gr = (size_t)(bm + row);
        if (RESID) v += resid[gr * 256 + col];
        if (OUTBF)
          ((ushort_t*)outp)[gr * 256 + col] = f2bf(v);
        else
          ((float*)outp)[gr * 256 + col] = v;
      }
}

// ---------------- KV = sum_s K^T V (per n,h), Ksum = sum_s K ----------------
__global__ __launch_bounds__(256) void kv_partial(
    const ushort_t* __restrict__ Kb, const ushort_t* __restrict__ Vb,
    float* __restrict__ kvp, float* __restrict__ ksp) {
  __shared__ float bufK[8][32];
  __shared__ float bufV[8][32];
  const int b = blockIdx.x;
  const int ch = b % KV_CHUNKS;
  const int nh = b / KV_CHUNKS;
  const int h = nh & 7, n = nh >> 3;
  const int tid = threadIdx.x;
  const int d = tid >> 3, vb = (tid & 7) * 4;
  const int ssl = tid >> 5, lane = tid & 31;
  float a0 = 0.f, a1 = 0.f, a2 = 0.f, a3 = 0.f, ks = 0.f;
  const size_t base = (size_t)n * SLEN * 256 + (size_t)h * 32;
  const int s0 = ch * KV_SC;
  for (int s = s0; s < s0 + KV_SC; s += 8) {
    __syncthreads();
    size_t idx = base + (size_t)(s + ssl) * 256 + lane;
    bufK[ssl][lane] = bf2f(Kb[idx]);
    bufV[ssl][lane] = bf2f(Vb[idx]);
    __syncthreads();
#pragma unroll
    for (int ss = 0; ss < 8; ++ss) {
      float kd = bufK[ss][d];
      float4 vv = *(const float4*)&bufV[ss][vb];
      a0 += kd * vv.x; a1 += kd * vv.y; a2 += kd * vv.z; a3 += kd * vv.w;
      ks += kd;
    }
  }
  float* kv = &kvp[(size_t)b * 1024 + d * 32 + vb];
  kv[0] = a0; kv[1] = a1; kv[2] = a2; kv[3] = a3;
  if ((tid & 7) == 0) ksp[(size_t)b * 32 + d] = ks;
}

__global__ __launch_bounds__(256) void kv_reduce(
    const float* __restrict__ kvp, const float* __restrict__ ksp,
    float* __restrict__ KV, float* __restrict__ Ksum) {
  const int nh = blockIdx.x;
  const int tid = threadIdx.x;
  for (int e = tid; e < 1024; e += 256) {
    float s = 0.f;
    for (int p = 0; p < KV_CHUNKS; ++p)
      s += kvp[(size_t)(nh * KV_CHUNKS + p) * 1024 + e];
    KV[(size_t)nh * 1024 + e] = s;
  }
  if (tid < 32) {
    float s = 0.f;
    for (int p = 0; p < KV_CHUNKS; ++p)
      s += ksp[(size_t)(nh * KV_CHUNKS + p) * 32 + tid];
    Ksum[nh * 32 + tid] = s;
  }
}

// msg[r, h*32+v] = (Q_h . KVcol_v) / (Q_h . Ksum_h + eps); 8 rows per block
__global__ __launch_bounds__(256) void msg_kernel(
    const ushort_t* __restrict__ Qb, const float* __restrict__ KV,
    const float* __restrict__ Ksum, ushort_t* __restrict__ msg) {
  __shared__ float Qs[8][256];
  __shared__ float Ks[8][32];
  const int b = blockIdx.x;   // 2400 blocks
  const int r0 = b * 8;
  const int n = r0 / SLEN;
  const int tid = threadIdx.x;
  Ks[tid >> 5][tid & 31] = Ksum[(n * 8 + (tid >> 5)) * 32 + (tid & 31)];
  for (int i = tid; i < 512; i += 256) {
    int rr = i >> 6, cc = (i & 63) << 2;
    const ushort4 u = *(const ushort4*)&Qb[(size_t)(r0 + rr) * 256 + cc];
    Qs[rr][cc + 0] = bf2f(u.x); Qs[rr][cc + 1] = bf2f(u.y);
    Qs[rr][cc + 2] = bf2f(u.z); Qs[rr][cc + 3] = bf2f(u.w);
  }
  __syncthreads();
  const int h = tid >> 5, v = tid & 31;
  const float* kvh = &KV[(size_t)(n * 8 + h) * 1024 + v];
  float kvc[32];
#pragma unroll
  for (int d = 0; d < 32; ++d) kvc[d] = kvh[d * 32];
#pragma unroll
  for (int rr = 0; rr < 8; ++rr) {
    float z = 0.f, m = 0.f;
#pragma unroll
    for (int d = 0; d < 32; ++d) {
      float qd = Qs[rr][h * 32 + d];
      z += qd * Ks[h][d];
      m += qd * kvc[d];
    }
    z = 1.0f / (z + 1e-6f);
    msg[(size_t)(r0 + rr) * 256 + h * 32 + v] = f2bf(m * z);
  }
}

// ------- fp32 -> bf16 conversions, one dispatch: [0,4800) x/src, rest W -----
__global__ __launch_bounds__(256) void conv_all(
    const float* __restrict__ x, const float* __restrict__ src,
    const float* w0, const float* w1, const float* w2, const float* w3,
    const float* w4, const float* w5,
    ushort_t* __restrict__ xo, ushort_t* __restrict__ so,
    ushort_t* o0, ushort_t* o1, ushort_t* o2, ushort_t* o3, ushort_t* o4,
    ushort_t* o5) {
  int blk = blockIdx.x;
  if (blk < 4800) {
    const float* s; ushort_t* d;
    if (blk < 2400) { s = x; d = xo; } else { s = src; d = so; blk -= 2400; }
    size_t o = ((size_t)blk * 256 + threadIdx.x) * 8;
    float4 v0 = *(const float4*)&s[o];
    float4 v1 = *(const float4*)&s[o + 4];
    ushort8 u = {f2bf(v0.x), f2bf(v0.y), f2bf(v0.z), f2bf(v0.w),
                 f2bf(v1.x), f2bf(v1.y), f2bf(v1.z), f2bf(v1.w)};
    *(ushort8*)&d[o] = u;
  } else {
    int e = ((blk - 4800) * 256 + threadIdx.x) * 4;
    const float* s; ushort_t* d; int off;
    if      (e < 65536)  { s = w0; d = o0; off = e; }
    else if (e < 131072) { s = w1; d = o1; off = e - 65536; }
    else if (e < 196608) { s = w2; d = o2; off = e - 131072; }
    else if (e < 262144) { s = w3; d = o3; off = e - 196608; }
    else if (e < 524288) { s = w4; d = o4; off = e - 262144; }
    else                 { s = w5; d = o5; off = e - 524288; }
    float4 v = *(const float4*)&s[off];
    ushort4 u = make_ushort4(f2bf(v.x), f2bf(v.y), f2bf(v.z), f2bf(v.w));
    *(ushort4*)&d[off] = u;
  }
}

extern "C" void kernel_launch(void* const* d_in, const int* in_sizes, int n_in,
                              void* d_out, int out_size, void* d_ws,
                              size_t ws_size, hipStream_t stream) {
  const float* x    = (const float*)d_in[0];
  const float* src  = (const float*)d_in[1];
  const float* x_pe = (const float*)d_in[2];
  const float* s_pe = (const float*)d_in[3];
  const float* Wq = (const float*)d_in[4];
  const float* Wk = (const float*)d_in[5];
  const float* Wv = (const float*)d_in[6];
  const float* Wm = (const float*)d_in[7];
  const float* W1 = (const float*)d_in[8];
  const float* W2 = (const float*)d_in[9];
  const float* g1 = (const float*)d_in[10];
  const float* b1 = (const float*)d_in[11];
  const float* g2 = (const float*)d_in[12];
  const float* b2 = (const float*)d_in[13];
  float* out = (float*)d_out;

  const size_t R = (size_t)NROWS * 256;  // 4,915,200
  ushort_t* xb    = (ushort_t*)d_ws;
  ushort_t* srcb  = xb + R;
  ushort_t* Qb    = srcb + R;
  ushort_t* Kb    = Qb + R;
  ushort_t* Vb    = Kb + R;
  ushort_t* msgln = Vb + R;
  ushort_t* Wqb   = msgln + R;
  ushort_t* Wkb   = Wqb + 65536;
  ushort_t* Wvb   = Wkb + 65536;
  ushort_t* Wmb   = Wvb + 65536;
  ushort_t* W1b   = Wmb + 65536;
  ushort_t* W2b   = W1b + 262144;
  float* kvp      = (float*)(W2b + 131072);   // 491520 f32
  float* ksp      = kvp + 491520;             // 15360
  float* KVb      = ksp + 15360;              // 32768
  float* Ksum     = KVb + 32768;              // 1024
  ushort_t* msgb = srcb;   // srcb dead after qkv
  ushort_t* h1   = Kb;     // Kb+Vb dead after kv_partial (2R contiguous)

  dim3 blk(256);
  conv_all<<<5440, blk, 0, stream>>>(x, src, Wq, Wk, Wv, Wm, W1, W2,
                                     xb, srcb, Wqb, Wkb, Wvb, Wmb, W1b, W2b);
  qkv_kernel<<<1800, blk, 24576, stream>>>(xb, srcb, Wqb, Wkb, Wvb, Qb, Kb, Vb,
                                           x_pe, s_pe);
  kv_partial<<<480, blk, 0, stream>>>(Kb, Vb, kvp, ksp);
  kv_reduce<<<32, blk, 0, stream>>>(kvp, ksp, KVb, Ksum);
  msg_kernel<<<2400, blk, 0, stream>>>(Qb, KVb, Ksum, msgb);
  // merge + LN1: msgln = LN(msg @ Wm.T) (bf16)
  gemm_ln_kernel<256, false, true><<<600, blk, 0, stream>>>(
      msgb, Wmb, g1, b1, nullptr, msgln);
  // MLP1: h1 = relu([xb, msgln] @ W1.T) (bf16, [19200,512])
  gemm_kernel<64, 3, true, true><<<1200, blk, 24576, stream>>>(
      xb, msgln, W1b, h1, nullptr, 512, 512, 256);
  // MLP2 + LN2 + residual: out = x + LN(h1 @ W2.T) (fp32)
  gemm_ln_kernel<512, true, false><<<600, blk, 0, stream>>>(
      h1, W2b, g2, b2, x, out);
}